// Round 7
// baseline (1600.766 us; speedup 1.0000x reference)
//
#include <hip/hip_runtime.h>
#include <stdint.h>
#include <stddef.h>

// ---------------------------------------------------------------------------
// WQLinear: out[M][N] = x[M][K] * W[N][K]^T + bias
//   M=4096, K=4096, N=11008; W = int4 AWQ dequant (group 128)
// Pass 1 (merged): dequant W -> bf16 ws; x -> bf16 ws (row-major).
// Pass 2: 256x256x64 GEMM, 4 waves x (128x128 wave tile), acc in AGPRs.
//   R0-R6 localized the wall: the 8-wave 128x64 structure is LDS-datapath
//   bound (192KB/CU/K-tile ~ 900cyc/phase vs 620 MFMA). 128x128 wave tiles
//   cut LDS traffic to 128KB/CU/K-tile; the 256-reg accumulator that killed
//   R2 (spill, 1.8GB scratch) is forced into AGPRs via inline-asm MFMA
//   ("+a" constraint); 1 wave/SIMD via __launch_bounds__(256,1) gives the
//   512-reg unified budget: 256 AGPR + ~180 VGPR, no spill.
//   Pipeline/staging/swizzle = R2's correctness-verified schedule, unchanged.
// ---------------------------------------------------------------------------

#define M_DIM 4096
#define N_DIM 11008
#define K_DIM 4096
#define NT    (K_DIM / 64)          // 64 K-tiles

typedef __bf16 bf16x8 __attribute__((ext_vector_type(8)));
typedef float f32x4 __attribute__((ext_vector_type(4)));
typedef unsigned int u32x4 __attribute__((ext_vector_type(4)));
typedef unsigned short u16x8 __attribute__((ext_vector_type(8)));
typedef unsigned short u16x4 __attribute__((ext_vector_type(4)));

__device__ __forceinline__ unsigned short f2bf(float f) {
    unsigned int u = __float_as_uint(f);
    u += 0x7fffu + ((u >> 16) & 1u);   // round-to-nearest-even
    return (unsigned short)(u >> 16);
}

typedef const __attribute__((address_space(1))) void* as1_cptr;
typedef __attribute__((address_space(3))) void* as3_ptr;

__device__ __forceinline__ void gl_lds16(const void* g, void* l) {
    __builtin_amdgcn_global_load_lds((as1_cptr)g, (as3_ptr)l, 16, 0, 0);
}

#define MFMA16(A, B, C) __builtin_amdgcn_mfma_f32_16x16x32_bf16((A), (B), (C), 0, 0, 0)

// MFMA with accumulator pinned to AGPRs (prevents the R2 spill).
__device__ __forceinline__ void mfma_a(f32x4& acc, bf16x8 a, bf16x8 b) {
    asm("v_mfma_f32_16x16x32_bf16 %0, %1, %2, %0"
        : "+a"(acc) : "v"(a), "v"(b));
}

// ---- merged pre-pass: blocks [0,22016) dequant W; [22016,30208) conv x ----
#define DQ_BLOCKS 22016
__global__ __launch_bounds__(256)
void prep_kernel(const int* __restrict__ qw, const int* __restrict__ qz,
                 const float* __restrict__ sc, unsigned short* __restrict__ Wbf,
                 const float* __restrict__ x, unsigned short* __restrict__ Xbf)
{
    if (blockIdx.x < DQ_BLOCKS) {
        int idx = blockIdx.x * 256 + threadIdx.x;
        int n = idx >> 9;          // K/8 = 512 packed per row
        int p = idx & 511;
        int g = p >> 4;            // group = (p*8)/128
        unsigned int zw = (unsigned int)qz[n * 4 + (g >> 3)];
        float z = (float)((zw >> ((g & 7) * 4)) & 15u);
        float s = sc[n * 32 + g];
        float nz = -z * s;
        unsigned int w = (unsigned int)__builtin_nontemporal_load(qw + idx);
        u16x8 t;
#pragma unroll
        for (int j = 0; j < 8; ++j) {
            float q = (float)((w >> (4 * j)) & 15u);
            t[j] = f2bf(__builtin_fmaf(q, s, nz));
        }
        *(u16x8*)(Wbf + (size_t)idx * 8) = t;
    } else {
        size_t i8 = ((size_t)(blockIdx.x - DQ_BLOCKS) * 256 + threadIdx.x) * 8;
        f32x4 a, b;
#pragma unroll
        for (int j = 0; j < 4; ++j) a[j] = __builtin_nontemporal_load(x + i8 + j);
#pragma unroll
        for (int j = 0; j < 4; ++j) b[j] = __builtin_nontemporal_load(x + i8 + 4 + j);
        u16x8 t;
#pragma unroll
        for (int j = 0; j < 4; ++j) t[j] = f2bf(a[j]);
#pragma unroll
        for (int j = 0; j < 4; ++j) t[4 + j] = f2bf(b[j]);
        *(u16x8*)(Xbf + i8) = t;
    }
}

// ---- main GEMM: 256x256 tile, BK=64, 4 waves (2x2), 128x128 wave tile ----
#define LDA_RD(BASE, fmc, kkc) \
    __builtin_bit_cast(bf16x8, *(const u32x4*)((BASE) + (fmc)*2048 + a_rd + (swz ^ ((kkc)*64))))
#define LDB_RD(BASE, fnc, kkc) \
    __builtin_bit_cast(bf16x8, *(const u32x4*)((BASE) + (fnc)*2048 + b_rd + (swz ^ ((kkc)*64))))

#define WAIT_BAR(N)                                         \
    asm volatile("s_waitcnt vmcnt(" #N ")" ::: "memory");   \
    __builtin_amdgcn_s_barrier();                           \
    asm volatile("" ::: "memory");                          \
    __builtin_amdgcn_s_setprio(1);

#define END_PHASE()                                         \
    __builtin_amdgcn_s_setprio(0);                          \
    asm volatile("s_waitcnt lgkmcnt(0)" ::: "memory");      \
    __builtin_amdgcn_sched_barrier(0);                      \
    __builtin_amdgcn_s_barrier();                           \
    asm volatile("" ::: "memory");

// stage one 16KB region (128 rows x 128B): 4 calls/wave x 4 waves
#define STAGE(GB, LB) do {                                  \
    gl_lds16((GB) + g_r0, (LB) + l_r0);                     \
    gl_lds16((GB) + g_r1, (LB) + l_r1);                     \
    gl_lds16((GB) + g_r2, (LB) + l_r2);                     \
    gl_lds16((GB) + g_r3, (LB) + l_r3); } while (0)

__global__ __launch_bounds__(256, 1)
void gemm256_kernel(const unsigned short* __restrict__ Xbf,
                    const unsigned short* __restrict__ Wbf,
                    const float* __restrict__ bias,
                    float* __restrict__ out)
{
    __shared__ u32x4 lds4[8192];            // 128 KiB
    char* ldsA = (char*)lds4;               // A: [2 buf][256 rows][128 B]
    char* ldsB = ldsA + 65536;              // B: [2 buf][256 rows][128 B]

    const int tid = threadIdx.x;
    const int lane = tid & 63, wid = tid >> 6;       // 4 waves
    const int l16 = lane & 15, g4 = lane >> 4;
    const int wm = wid >> 1, wn = wid & 1;           // 2x2 wave grid

    // XCD-aware bijective swizzle: 688 blocks = 8 XCD x 86; per XCD 2x43
    // rectangle walked column-major.
    const int bid = blockIdx.x;
    const int xcd = bid & 7, c = bid >> 3;
    const int tm = 2 * xcd + (c & 1), tn = c >> 1;
    const int m0 = tm * 256, n0 = tn * 256;

    const int swz  = (g4 ^ (l16 & 7)) << 4;            // read-side XOR (bytes)
    const int a_rd = (wm * 128 + l16) * 128;           // wave A rows: wm*128..+127
    const int b_rd = (wn * 128 + l16) * 128;           // wave B rows: wn*128..+127
    // inverse-swizzled per-lane global offset (linear LDS dst, swizzled src)
    const size_t goff = (size_t)(lane >> 3) * 8192 + (size_t)(((lane & 7) ^ (lane >> 3)) << 4);

    const char* pAg = (const char*)Xbf + (size_t)m0 * 8192 + goff;
    const char* pBg = (const char*)Wbf + (size_t)n0 * 8192 + goff;
    // per-wave staging row split: wave wid covers 8-row groups {wid, wid+4, wid+8, wid+12}
    const size_t g_r0 = (size_t)(wid)      * 65536;
    const size_t g_r1 = (size_t)(wid + 4)  * 65536;
    const size_t g_r2 = (size_t)(wid + 8)  * 65536;
    const size_t g_r3 = (size_t)(wid + 12) * 65536;
    const int l_r0 = (wid)      * 1024;
    const int l_r1 = (wid + 4)  * 1024;
    const int l_r2 = (wid + 8)  * 1024;
    const int l_r3 = (wid + 12) * 1024;

    // accumulators: 4 quadrants of the 128x128 wave tile, 16 frags each (AGPR)
    f32x4 aLL[4][4], aLH[4][4], aHL[4][4], aHH[4][4];
#pragma unroll
    for (int i = 0; i < 4; ++i)
#pragma unroll
        for (int j = 0; j < 4; ++j) {
            aLL[i][j] = f32x4{0.f, 0.f, 0.f, 0.f};
            aLH[i][j] = f32x4{0.f, 0.f, 0.f, 0.f};
            aHL[i][j] = f32x4{0.f, 0.f, 0.f, 0.f};
            aHH[i][j] = f32x4{0.f, 0.f, 0.f, 0.f};
        }

    float bv[8];
#pragma unroll
    for (int q = 0; q < 8; ++q)
        bv[q] = bias[n0 + wn * 128 + q * 16 + l16];

    bf16x8 aL[4][2], aH[4][2], bL[4][2], bH[4][2];

    // ---- prologue: stage tiles 0 and 1, region order [Bs0, As0, Bs1, As1] ----
    STAGE(pBg,                 ldsB);
    STAGE(pAg,                 ldsA);
    STAGE(pBg + 1048576,       ldsB + 16384);
    STAGE(pAg + 1048576,       ldsA + 16384);
    STAGE(pBg + 128,           ldsB + 32768);
    STAGE(pAg + 128,           ldsA + 32768);
    STAGE(pBg + 1048576 + 128, ldsB + 49152);
    STAGE(pAg + 1048576 + 128, ldsA + 49152);
    asm volatile("s_waitcnt vmcnt(16)" ::: "memory");   // all of tile 0 landed
    __builtin_amdgcn_s_barrier();
    asm volatile("" ::: "memory");
    // prologue reads: aL(0), bL(0)
#pragma unroll
    for (int fm = 0; fm < 4; ++fm) {
        aL[fm][0] = LDA_RD(ldsA, fm, 0);
        aL[fm][1] = LDA_RD(ldsA, fm, 1);
    }
#pragma unroll
    for (int fn = 0; fn < 4; ++fn) {
        bL[fn][0] = LDB_RD(ldsB, fn, 0);
        bL[fn][1] = LDB_RD(ldsB, fn, 1);
    }
    asm volatile("s_waitcnt lgkmcnt(0)" ::: "memory");
    __builtin_amdgcn_sched_barrier(0);
    __builtin_amdgcn_s_barrier();
    asm volatile("" ::: "memory");

#pragma unroll 2
    for (int t = 0; t < NT; ++t) {
        const int p = t & 1;
        char* Ap = ldsA + p * 32768;
        char* Bp = ldsB + p * 32768;
        char* An = ldsA + (p ^ 1) * 32768;
        char* Bn = ldsB + (p ^ 1) * 32768;
        const size_t k2 = (size_t)((t + 2 < NT ? t + 2 : NT - 1) * 128);

        // == phase 0: Q00 = aL*bL ; read bH(t) ; no staging ==
        WAIT_BAR(12);                              // lands Bs0(t+1)
#pragma unroll
        for (int fn = 0; fn < 4; ++fn) {
            bH[fn][0] = LDB_RD(Bp, 4 + fn, 0);
            bH[fn][1] = LDB_RD(Bp, 4 + fn, 1);
        }
#pragma unroll
        for (int kk = 0; kk < 2; ++kk)
#pragma unroll
            for (int fm = 0; fm < 4; ++fm)
#pragma unroll
                for (int fn = 0; fn < 4; ++fn)
                    mfma_a(aLL[fm][fn], aL[fm][kk], bL[fn][kk]);
        END_PHASE();

        // == phase 1: Q01 = aL*bH ; read aH(t) ; issue Bs0(t+2) -> Bp ==
        STAGE(pBg + k2, Bp);
        WAIT_BAR(8);                               // lands As0(t+1), Bs1(t+1)
#pragma unroll
        for (int fm = 0; fm < 4; ++fm) {
            aH[fm][0] = LDA_RD(Ap, 4 + fm, 0);
            aH[fm][1] = LDA_RD(Ap, 4 + fm, 1);
        }
#pragma unroll
        for (int kk = 0; kk < 2; ++kk)
#pragma unroll
            for (int fm = 0; fm < 4; ++fm)
#pragma unroll
                for (int fn = 0; fn < 4; ++fn)
                    mfma_a(aLH[fm][fn], aL[fm][kk], bH[fn][kk]);
        END_PHASE();

        // == phase 2: Q10 = aH*bL ; read aL(t+1) ; issue As0(t+2)->Ap, Bs1(t+2)->Bp+16K ==
        STAGE(pAg + k2, Ap);
        STAGE(pBg + 1048576 + k2, Bp + 16384);
        WAIT_BAR(12);                              // lands As1(t+1)
#pragma unroll
        for (int fm = 0; fm < 4; ++fm) {
            aL[fm][0] = LDA_RD(An, fm, 0);
            aL[fm][1] = LDA_RD(An, fm, 1);
        }
#pragma unroll
        for (int kk = 0; kk < 2; ++kk)
#pragma unroll
            for (int fm = 0; fm < 4; ++fm)
#pragma unroll
                for (int fn = 0; fn < 4; ++fn)
                    mfma_a(aHL[fm][fn], aH[fm][kk], bL[fn][kk]);
        END_PHASE();

        // == phase 3: Q11 = aH*bH ; read bL(t+1) ; issue As1(t+2) -> Ap+16K ==
        STAGE(pAg + 1048576 + k2, Ap + 16384);
        WAIT_BAR(16);                              // no-op (steady outstanding = 16)
#pragma unroll
        for (int fn = 0; fn < 4; ++fn) {
            bL[fn][0] = LDB_RD(Bn, fn, 0);
            bL[fn][1] = LDB_RD(Bn, fn, 1);
        }
#pragma unroll
        for (int kk = 0; kk < 2; ++kk)
#pragma unroll
            for (int fm = 0; fm < 4; ++fm)
#pragma unroll
                for (int fn = 0; fn < 4; ++fn)
                    mfma_a(aHH[fm][fn], aH[fm][kk], bH[fn][kk]);
        END_PHASE();
    }

    asm volatile("s_waitcnt vmcnt(0)" ::: "memory");   // drain dummy restage

    // epilogue: C/D layout col=lane&15, row=(lane>>4)*4+reg
#pragma unroll
    for (int fm = 0; fm < 4; ++fm) {
#pragma unroll
        for (int fn = 0; fn < 4; ++fn) {
#pragma unroll
            for (int QM = 0; QM < 2; ++QM) {
                size_t r0 = (size_t)(m0 + wm * 128 + QM * 64 + fm * 16 + g4 * 4);
#pragma unroll
                for (int QN = 0; QN < 2; ++QN) {
                    int col = n0 + wn * 128 + QN * 64 + fn * 16 + l16;
                    f32x4 v = (QM == 0)
                                ? ((QN == 0) ? aLL[fm][fn] : aLH[fm][fn])
                                : ((QN == 0) ? aHL[fm][fn] : aHH[fm][fn]);
                    float bb = bv[QN * 4 + fn];
#pragma unroll
                    for (int r = 0; r < 4; ++r)
                        out[(r0 + r) * N_DIM + col] = v[r] + bb;
                }
            }
        }
    }
}

// ---- fallback (no-ws): round-1 fused-dequant 128^2 kernel (verified) ----
__global__ __launch_bounds__(256, 2)
void gemm_fallback(const float* __restrict__ x,
                   const int* __restrict__ qweight,
                   const int* __restrict__ qzeros,
                   const float* __restrict__ scales,
                   const float* __restrict__ bias,
                   float* __restrict__ out)
{
    __shared__ u32x4 lds_raw[2048];
    char* ldsA = (char*)lds_raw;
    char* ldsB = ldsA + 16384;

    const int tid = threadIdx.x;
    const int n0 = blockIdx.x * 128;
    const int m0 = blockIdx.y * 128;
    const int wave = tid >> 6;
    const int lane = tid & 63;
    const int l16 = lane & 15;
    const int g4 = lane >> 4;
    const int wm = wave >> 1;
    const int wn = wave & 1;

    f32x4 acc[4][4];
#pragma unroll
    for (int i = 0; i < 4; ++i)
#pragma unroll
        for (int j = 0; j < 4; ++j) acc[i][j] = f32x4{0.f, 0.f, 0.f, 0.f};

    for (int kt = 0; kt < K_DIM / 64; ++kt) {
        __syncthreads();
#pragma unroll
        for (int i = 0; i < 4; ++i) {
            int cI = tid + i * 256;
            int row = cI >> 4, cc = cI & 15;
            f32x4 v = *(const f32x4*)(x + ((size_t)(m0 + row) * K_DIM + kt * 64 + cc * 4));
            u16x4 h;
#pragma unroll
            for (int j = 0; j < 4; ++j) h[j] = f2bf(v[j]);
            int b = row * 128 + cc * 8;
            *(u16x4*)(ldsA + (b ^ ((row & 7) << 4))) = h;
        }
        {
            int row = tid >> 1, half = tid & 1;
            int n = n0 + row;
            int g = kt >> 1;
            unsigned int zw = (unsigned int)qzeros[n * 4 + (g >> 3)];
            float z = (float)((zw >> ((g & 7) * 4)) & 15u);
            float s = scales[n * 32 + g];
            float nz = -z * s;
            u32x4 w4 = *(const u32x4*)(qweight + (size_t)n * 512 + kt * 8 + half * 4);
#pragma unroll
            for (int j4 = 0; j4 < 4; ++j4) {
                unsigned int w = w4[j4];
                u16x8 tt;
#pragma unroll
                for (int j = 0; j < 8; ++j) {
                    float q = (float)((w >> (4 * j)) & 15u);
                    tt[j] = f2bf(__builtin_fmaf(q, s, nz));
                }
                int b = row * 128 + half * 64 + j4 * 16;
                *(u16x8*)(ldsB + (b ^ ((row & 7) << 4))) = tt;
            }
        }
        __syncthreads();

#pragma unroll
        for (int kk = 0; kk < 2; ++kk) {
            bf16x8 af[4], bfm[4];
#pragma unroll
            for (int fm = 0; fm < 4; ++fm) {
                int arow = wm * 64 + fm * 16 + l16;
                int ab = arow * 128 + kk * 64 + g4 * 16;
                af[fm] = __builtin_bit_cast(bf16x8, *(const u32x4*)(ldsA + (ab ^ ((arow & 7) << 4))));
            }
#pragma unroll
            for (int fn = 0; fn < 4; ++fn) {
                int brow = wn * 64 + fn * 16 + l16;
                int bb = brow * 128 + kk * 64 + g4 * 16;
                bfm[fn] = __builtin_bit_cast(bf16x8, *(const u32x4*)(ldsB + (bb ^ ((brow & 7) << 4))));
            }
#pragma unroll
            for (int fm = 0; fm < 4; ++fm)
#pragma unroll
                for (int fn = 0; fn < 4; ++fn)
                    acc[fm][fn] = MFMA16(af[fm], bfm[fn], acc[fm][fn]);
        }
    }

#pragma unroll
    for (int fm = 0; fm < 4; ++fm) {
        int row0 = m0 + wm * 64 + fm * 16 + g4 * 4;
#pragma unroll
        for (int fn = 0; fn < 4; ++fn) {
            int col = n0 + wn * 64 + fn * 16 + l16;
            float bvv = bias[col];
            f32x4 a = acc[fm][fn];
#pragma unroll
            for (int r = 0; r < 4; ++r)
                out[(size_t)(row0 + r) * N_DIM + col] = a[r] + bvv;
        }
    }
}

extern "C" void kernel_launch(void* const* d_in, const int* in_sizes, int n_in,
                              void* d_out, int out_size, void* d_ws, size_t ws_size,
                              hipStream_t stream)
{
    const float* x      = (const float*)d_in[0];
    const int* qweight  = (const int*)d_in[1];
    const int* qzeros   = (const int*)d_in[2];
    const float* scales = (const float*)d_in[3];
    const float* bias   = (const float*)d_in[4];
    float* out          = (float*)d_out;

    const size_t WB = (size_t)N_DIM * K_DIM * 2;
    const size_t XB = (size_t)M_DIM * K_DIM * 2;

    if (ws_size >= WB + XB) {
        unsigned short* Wbf = (unsigned short*)d_ws;
        unsigned short* Xbf = (unsigned short*)((char*)d_ws + WB);
        prep_kernel<<<dim3(30208), dim3(256), 0, stream>>>(qweight, qzeros, scales,
                                                           Wbf, x, Xbf);
        gemm256_kernel<<<dim3(688), dim3(256), 0, stream>>>(Xbf, Wbf, bias, out);
    } else {
        dim3 grid(N_DIM / 128, M_DIM / 128);
        gemm_fallback<<<grid, dim3(256), 0, stream>>>(x, qweight, qzeros, scales, bias, out);
    }
}

// Round 8
// 339.774 us; speedup vs baseline: 4.7113x; 4.7113x over previous
//
#include <hip/hip_runtime.h>
#include <stdint.h>
#include <stddef.h>

// ---------------------------------------------------------------------------
// WQLinear: out[M][N] = x[M][K] * W[N][K]^T + bias
//   M=4096, K=4096, N=11008; W = int4 AWQ dequant (group 128)
// Pass 1 (merged, single dispatch): dequant W -> bf16 ws; x -> bf16 ws.
// Pass 2: R0's 256x256x64 8-wave MFMA GEMM (128x64 wave tiles), 4-phase
//   read-ahead pipeline -- byte-identical to the best-measured 325us K-loop,
//   plain epilogue stores (nt stores regressed: R6 325->332, WRITE +31MB).
// Session ledger: R1 32x32 MFMA -44%; R2/R7 128x128 wave tile = reg spill
//   (intrinsic AND "+a" asm); R3 barrier halving +-0; R4 B-direct -9%;
//   R5 2 blocks/CU -17%; R6 nt stores -2% gemm, merged prep -10us total.
//   This is the measured optimum combination of all tested variants.
// ---------------------------------------------------------------------------

#define M_DIM 4096
#define N_DIM 11008
#define K_DIM 4096
#define NT    (K_DIM / 64)          // 64 K-tiles

typedef __bf16 bf16x8 __attribute__((ext_vector_type(8)));
typedef float f32x4 __attribute__((ext_vector_type(4)));
typedef unsigned int u32x4 __attribute__((ext_vector_type(4)));
typedef unsigned short u16x8 __attribute__((ext_vector_type(8)));
typedef unsigned short u16x4 __attribute__((ext_vector_type(4)));

__device__ __forceinline__ unsigned short f2bf(float f) {
    unsigned int u = __float_as_uint(f);
    u += 0x7fffu + ((u >> 16) & 1u);   // round-to-nearest-even
    return (unsigned short)(u >> 16);
}

typedef const __attribute__((address_space(1))) void* as1_cptr;
typedef __attribute__((address_space(3))) void* as3_ptr;

__device__ __forceinline__ void gl_lds16(const void* g, void* l) {
    __builtin_amdgcn_global_load_lds((as1_cptr)g, (as3_ptr)l, 16, 0, 0);
}

#define MFMA16(A, B, C) __builtin_amdgcn_mfma_f32_16x16x32_bf16((A), (B), (C), 0, 0, 0)

// ---- merged pre-pass: blocks [0,22016) dequant W; [22016,30208) conv x ----
#define DQ_BLOCKS 22016
__global__ __launch_bounds__(256)
void prep_kernel(const int* __restrict__ qw, const int* __restrict__ qz,
                 const float* __restrict__ sc, unsigned short* __restrict__ Wbf,
                 const float* __restrict__ x, unsigned short* __restrict__ Xbf)
{
    if (blockIdx.x < DQ_BLOCKS) {
        // dequant W: int4 -> bf16 row-major [N][K]
        int idx = blockIdx.x * 256 + threadIdx.x;
        int n = idx >> 9;          // K/8 = 512 packed per row
        int p = idx & 511;
        int g = p >> 4;            // group = (p*8)/128
        unsigned int zw = (unsigned int)qz[n * 4 + (g >> 3)];
        float z = (float)((zw >> ((g & 7) * 4)) & 15u);
        float s = sc[n * 32 + g];
        float nz = -z * s;
        unsigned int w = (unsigned int)__builtin_nontemporal_load(qw + idx);
        u16x8 t;
#pragma unroll
        for (int j = 0; j < 8; ++j) {
            float q = (float)((w >> (4 * j)) & 15u);
            t[j] = f2bf(__builtin_fmaf(q, s, nz));
        }
        *(u16x8*)(Wbf + (size_t)idx * 8) = t;
    } else {
        // conv x: fp32 -> bf16 row-major [M][K]
        size_t i8 = ((size_t)(blockIdx.x - DQ_BLOCKS) * 256 + threadIdx.x) * 8;
        f32x4 a, b;
#pragma unroll
        for (int j = 0; j < 4; ++j) a[j] = __builtin_nontemporal_load(x + i8 + j);
#pragma unroll
        for (int j = 0; j < 4; ++j) b[j] = __builtin_nontemporal_load(x + i8 + 4 + j);
        u16x8 t;
#pragma unroll
        for (int j = 0; j < 4; ++j) t[j] = f2bf(a[j]);
#pragma unroll
        for (int j = 0; j < 4; ++j) t[4 + j] = f2bf(b[j]);
        *(u16x8*)(Xbf + i8) = t;
    }
}

// ---- main GEMM: 256x256 tile, BK=64, 8 waves (2x4), read-ahead pipeline ----
// (byte-identical K-loop to the 325us R0 kernel; plain epilogue stores)
#define LDA_RD(BASE, MHc, fmc, kkc) \
    __builtin_bit_cast(bf16x8, *(const u32x4*)((BASE) + (MHc)*16384 + (fmc)*2048 + a_rd + (swz ^ ((kkc)*64))))
#define LDB_RD(BASE, NHc, fnc, kkc) \
    __builtin_bit_cast(bf16x8, *(const u32x4*)((BASE) + (NHc)*16384 + (fnc)*2048 + b_rd + (swz ^ ((kkc)*64))))

#define WAIT_BAR1()                                         \
    asm volatile("s_waitcnt vmcnt(12)" ::: "memory");       \
    __builtin_amdgcn_s_barrier();                           \
    asm volatile("" ::: "memory");                          \
    __builtin_amdgcn_s_setprio(1);

#define END_PHASE()                                         \
    __builtin_amdgcn_s_setprio(0);                          \
    asm volatile("s_waitcnt lgkmcnt(0)" ::: "memory");      \
    __builtin_amdgcn_sched_barrier(0);                      \
    __builtin_amdgcn_s_barrier();                           \
    asm volatile("" ::: "memory");

__global__ __launch_bounds__(512, 2)
void gemm256_kernel(const unsigned short* __restrict__ Xbf,
                    const unsigned short* __restrict__ Wbf,
                    const float* __restrict__ bias,
                    float* __restrict__ out)
{
    __shared__ u32x4 lds4[8192];            // 128 KiB
    char* ldsA = (char*)lds4;               // A: [2 buf][256 rows][128 B]
    char* ldsB = ldsA + 65536;              // B: [2 buf][256 rows][128 B]

    const int tid = threadIdx.x;
    const int lane = tid & 63, wid = tid >> 6;
    const int l16 = lane & 15, g4 = lane >> 4;
    const int wm = wid >> 2, wn = wid & 3;

    // XCD-aware bijective swizzle: 688 blocks = 8 XCD x 86; per XCD 2x43
    // rectangle walked column-major.
    const int bid = blockIdx.x;
    const int xcd = bid & 7, c = bid >> 3;
    const int tm = 2 * xcd + (c & 1), tn = c >> 1;
    const int m0 = tm * 256, n0 = tn * 256;

    const int swz  = (g4 ^ (l16 & 7)) << 4;            // read-side XOR (bytes)
    const int a_rd = (wm * 64 + l16) * 128;
    const int b_rd = (wn * 32 + l16) * 128;
    // inverse-swizzled per-lane global offset (linear LDS dst, swizzled src)
    const size_t goff = (size_t)(lane >> 3) * 8192 + (size_t)(((lane & 7) ^ (lane >> 3)) << 4);

    const char* pAg = (const char*)Xbf + (size_t)m0 * 8192 + goff;
    const char* pBg = (const char*)Wbf + (size_t)n0 * 8192 + goff;
    const size_t rowA = (size_t)(wid * 8) * 8192;       // rows 0-63 (8/wave)
    const size_t rowB = (size_t)((wid + 8) * 8) * 8192; // rows 64-127
    const int ldst0 = wid * 1024, ldst1 = (wid + 8) * 1024;

    f32x4 acc[8][4];
#pragma unroll
    for (int i = 0; i < 8; ++i)
#pragma unroll
        for (int j = 0; j < 4; ++j) acc[i][j] = f32x4{0.f, 0.f, 0.f, 0.f};

    float bvv[4];
#pragma unroll
    for (int q = 0; q < 4; ++q)
        bvv[q] = bias[n0 + (q >> 1) * 128 + wn * 32 + (q & 1) * 16 + l16];

    bf16x8 a0[4][2], a1[4][2], b0[2][2], b1[2][2];

    // ---- prologue: stage tiles 0 and 1 (order A_s0,B_s0,B_s1,A_s1 each) ----
    gl_lds16(pAg + rowA, ldsA + ldst0);
    gl_lds16(pAg + rowB, ldsA + ldst1);
    gl_lds16(pBg + rowA, ldsB + ldst0);
    gl_lds16(pBg + rowB, ldsB + ldst1);
    gl_lds16(pBg + 1048576 + rowA, ldsB + 16384 + ldst0);
    gl_lds16(pBg + 1048576 + rowB, ldsB + 16384 + ldst1);
    gl_lds16(pAg + 1048576 + rowA, ldsA + 16384 + ldst0);
    gl_lds16(pAg + 1048576 + rowB, ldsA + 16384 + ldst1);
    gl_lds16(pAg + rowA + 128, ldsA + 32768 + ldst0);
    gl_lds16(pAg + rowB + 128, ldsA + 32768 + ldst1);
    gl_lds16(pBg + rowA + 128, ldsB + 32768 + ldst0);
    gl_lds16(pBg + rowB + 128, ldsB + 32768 + ldst1);
    gl_lds16(pBg + 1048576 + rowA + 128, ldsB + 49152 + ldst0);
    gl_lds16(pBg + 1048576 + rowB + 128, ldsB + 49152 + ldst1);
    gl_lds16(pAg + 1048576 + rowA + 128, ldsA + 49152 + ldst0);
    gl_lds16(pAg + 1048576 + rowB + 128, ldsA + 49152 + ldst1);
    asm volatile("s_waitcnt vmcnt(12)" ::: "memory");   // A_s0(0), B_s0(0) landed
    __builtin_amdgcn_s_barrier();
    asm volatile("" ::: "memory");
    // prologue reads: a0(0), b0(0) from buffer 0
#pragma unroll
    for (int fm = 0; fm < 4; ++fm) {
        a0[fm][0] = LDA_RD(ldsA, 0, fm, 0);
        a0[fm][1] = LDA_RD(ldsA, 0, fm, 1);
    }
#pragma unroll
    for (int fn = 0; fn < 2; ++fn) {
        b0[fn][0] = LDB_RD(ldsB, 0, fn, 0);
        b0[fn][1] = LDB_RD(ldsB, 0, fn, 1);
    }
    asm volatile("s_waitcnt lgkmcnt(0)" ::: "memory");
    __builtin_amdgcn_sched_barrier(0);
    __builtin_amdgcn_s_barrier();
    asm volatile("" ::: "memory");

#pragma unroll 2
    for (int t = 0; t < NT; ++t) {
        const int p = t & 1;
        char* Ap = ldsA + p * 32768;
        char* Bp = ldsB + p * 32768;
        char* An = ldsA + (p ^ 1) * 32768;
        char* Bn = ldsB + (p ^ 1) * 32768;
        const size_t k2 = (size_t)((t + 2 < NT ? t + 2 : NT - 1) * 128);

        // == phase 0: Q00 = a0*b0 ; read b1(t) ; issue A_s0(t+2) -> Ap ==
        gl_lds16(pAg + rowA + k2, Ap + ldst0);
        gl_lds16(pAg + rowB + k2, Ap + ldst1);
        WAIT_BAR1();
#pragma unroll
        for (int fn = 0; fn < 2; ++fn) {
            b1[fn][0] = LDB_RD(Bp, 1, fn, 0);
            b1[fn][1] = LDB_RD(Bp, 1, fn, 1);
        }
#pragma unroll
        for (int fm = 0; fm < 4; ++fm)
#pragma unroll
            for (int fn = 0; fn < 2; ++fn) {
                acc[fm][fn] = MFMA16(a0[fm][0], b0[fn][0], acc[fm][fn]);
                acc[fm][fn] = MFMA16(a0[fm][1], b0[fn][1], acc[fm][fn]);
            }
        END_PHASE();

        // == phase 1: Q01 = a0*b1 ; read a1(t) ; issue B_s0(t+2) -> Bp ==
        gl_lds16(pBg + rowA + k2, Bp + ldst0);
        gl_lds16(pBg + rowB + k2, Bp + ldst1);
        WAIT_BAR1();
#pragma unroll
        for (int fm = 0; fm < 4; ++fm) {
            a1[fm][0] = LDA_RD(Ap, 1, fm, 0);
            a1[fm][1] = LDA_RD(Ap, 1, fm, 1);
        }
#pragma unroll
        for (int fm = 0; fm < 4; ++fm)
#pragma unroll
            for (int fn = 0; fn < 2; ++fn) {
                acc[fm][2 + fn] = MFMA16(a0[fm][0], b1[fn][0], acc[fm][2 + fn]);
                acc[fm][2 + fn] = MFMA16(a0[fm][1], b1[fn][1], acc[fm][2 + fn]);
            }
        END_PHASE();

        // == phase 2: Q10 = a1*b0 ; read a0(t+1) kk=0 ; issue B_s1(t+2) -> Bp+16K ==
        gl_lds16(pBg + 1048576 + rowA + k2, Bp + 16384 + ldst0);
        gl_lds16(pBg + 1048576 + rowB + k2, Bp + 16384 + ldst1);
        WAIT_BAR1();
#pragma unroll
        for (int fm = 0; fm < 4; ++fm)
            a0[fm][0] = LDA_RD(An, 0, fm, 0);
#pragma unroll
        for (int fm = 0; fm < 4; ++fm)
#pragma unroll
            for (int fn = 0; fn < 2; ++fn) {
                acc[4 + fm][fn] = MFMA16(a1[fm][0], b0[fn][0], acc[4 + fm][fn]);
                acc[4 + fm][fn] = MFMA16(a1[fm][1], b0[fn][1], acc[4 + fm][fn]);
            }
        END_PHASE();

        // == phase 3: Q11 = a1*b1 ; read a0(t+1) kk=1 + b0(t+1) ; issue A_s1(t+2) -> Ap+16K ==
        gl_lds16(pAg + 1048576 + rowA + k2, Ap + 16384 + ldst0);
        gl_lds16(pAg + 1048576 + rowB + k2, Ap + 16384 + ldst1);
        WAIT_BAR1();
#pragma unroll
        for (int fm = 0; fm < 4; ++fm)
            a0[fm][1] = LDA_RD(An, 0, fm, 1);
#pragma unroll
        for (int fn = 0; fn < 2; ++fn) {
            b0[fn][0] = LDB_RD(Bn, 0, fn, 0);
            b0[fn][1] = LDB_RD(Bn, 0, fn, 1);
        }
#pragma unroll
        for (int fm = 0; fm < 4; ++fm)
#pragma unroll
            for (int fn = 0; fn < 2; ++fn) {
                acc[4 + fm][2 + fn] = MFMA16(a1[fm][0], b1[fn][0], acc[4 + fm][2 + fn]);
                acc[4 + fm][2 + fn] = MFMA16(a1[fm][1], b1[fn][1], acc[4 + fm][2 + fn]);
            }
        END_PHASE();
    }

    asm volatile("s_waitcnt vmcnt(0)" ::: "memory");   // drain dummy restage

    // epilogue: C/D layout col=lane&15, row=(lane>>4)*4+reg
#pragma unroll
    for (int MH = 0; MH < 2; ++MH)
#pragma unroll
        for (int fm = 0; fm < 4; ++fm) {
            size_t r0 = (size_t)(m0 + MH * 128 + wm * 64 + fm * 16 + g4 * 4);
#pragma unroll
            for (int NH = 0; NH < 2; ++NH)
#pragma unroll
                for (int fn = 0; fn < 2; ++fn) {
                    int col = n0 + NH * 128 + wn * 32 + fn * 16 + l16;
                    f32x4 v = acc[MH * 4 + fm][NH * 2 + fn];
                    float bb = bvv[NH * 2 + fn];
#pragma unroll
                    for (int r = 0; r < 4; ++r)
                        out[(r0 + r) * N_DIM + col] = v[r] + bb;
                }
        }
}

// ---- fallback (no-ws): round-1 fused-dequant 128^2 kernel (verified) ----
__global__ __launch_bounds__(256, 2)
void gemm_fallback(const float* __restrict__ x,
                   const int* __restrict__ qweight,
                   const int* __restrict__ qzeros,
                   const float* __restrict__ scales,
                   const float* __restrict__ bias,
                   float* __restrict__ out)
{
    __shared__ u32x4 lds_raw[2048];
    char* ldsA = (char*)lds_raw;
    char* ldsB = ldsA + 16384;

    const int tid = threadIdx.x;
    const int n0 = blockIdx.x * 128;
    const int m0 = blockIdx.y * 128;
    const int wave = tid >> 6;
    const int lane = tid & 63;
    const int l16 = lane & 15;
    const int g4 = lane >> 4;
    const int wm = wave >> 1;
    const int wn = wave & 1;

    f32x4 acc[4][4];
#pragma unroll
    for (int i = 0; i < 4; ++i)
#pragma unroll
        for (int j = 0; j < 4; ++j) acc[i][j] = f32x4{0.f, 0.f, 0.f, 0.f};

    for (int kt = 0; kt < K_DIM / 64; ++kt) {
        __syncthreads();
#pragma unroll
        for (int i = 0; i < 4; ++i) {
            int cI = tid + i * 256;
            int row = cI >> 4, cc = cI & 15;
            f32x4 v = *(const f32x4*)(x + ((size_t)(m0 + row) * K_DIM + kt * 64 + cc * 4));
            u16x4 h;
#pragma unroll
            for (int j = 0; j < 4; ++j) h[j] = f2bf(v[j]);
            int b = row * 128 + cc * 8;
            *(u16x4*)(ldsA + (b ^ ((row & 7) << 4))) = h;
        }
        {
            int row = tid >> 1, half = tid & 1;
            int n = n0 + row;
            int g = kt >> 1;
            unsigned int zw = (unsigned int)qzeros[n * 4 + (g >> 3)];
            float z = (float)((zw >> ((g & 7) * 4)) & 15u);
            float s = scales[n * 32 + g];
            float nz = -z * s;
            u32x4 w4 = *(const u32x4*)(qweight + (size_t)n * 512 + kt * 8 + half * 4);
#pragma unroll
            for (int j4 = 0; j4 < 4; ++j4) {
                unsigned int w = w4[j4];
                u16x8 tt;
#pragma unroll
                for (int j = 0; j < 8; ++j) {
                    float q = (float)((w >> (4 * j)) & 15u);
                    tt[j] = f2bf(__builtin_fmaf(q, s, nz));
                }
                int b = row * 128 + half * 64 + j4 * 16;
                *(u16x8*)(ldsB + (b ^ ((row & 7) << 4))) = tt;
            }
        }
        __syncthreads();

#pragma unroll
        for (int kk = 0; kk < 2; ++kk) {
            bf16x8 af[4], bfm[4];
#pragma unroll
            for (int fm = 0; fm < 4; ++fm) {
                int arow = wm * 64 + fm * 16 + l16;
                int ab = arow * 128 + kk * 64 + g4 * 16;
                af[fm] = __builtin_bit_cast(bf16x8, *(const u32x4*)(ldsA + (ab ^ ((arow & 7) << 4))));
            }
#pragma unroll
            for (int fn = 0; fn < 4; ++fn) {
                int brow = wn * 64 + fn * 16 + l16;
                int bb = brow * 128 + kk * 64 + g4 * 16;
                bfm[fn] = __builtin_bit_cast(bf16x8, *(const u32x4*)(ldsB + (bb ^ ((brow & 7) << 4))));
            }
#pragma unroll
            for (int fm = 0; fm < 4; ++fm)
#pragma unroll
                for (int fn = 0; fn < 4; ++fn)
                    acc[fm][fn] = MFMA16(af[fm], bfm[fn], acc[fm][fn]);
        }
    }

#pragma unroll
    for (int fm = 0; fm < 4; ++fm) {
        int row0 = m0 + wm * 64 + fm * 16 + g4 * 4;
#pragma unroll
        for (int fn = 0; fn < 4; ++fn) {
            int col = n0 + wn * 64 + fn * 16 + l16;
            float bv = bias[col];
            f32x4 a = acc[fm][fn];
#pragma unroll
            for (int r = 0; r < 4; ++r)
                out[(size_t)(row0 + r) * N_DIM + col] = a[r] + bv;
        }
    }
}

extern "C" void kernel_launch(void* const* d_in, const int* in_sizes, int n_in,
                              void* d_out, int out_size, void* d_ws, size_t ws_size,
                              hipStream_t stream)
{
    const float* x      = (const float*)d_in[0];
    const int* qweight  = (const int*)d_in[1];
    const int* qzeros   = (const int*)d_in[2];
    const float* scales = (const float*)d_in[3];
    const float* bias   = (const float*)d_in[4];
    float* out          = (float*)d_out;

    const size_t WB = (size_t)N_DIM * K_DIM * 2;
    const size_t XB = (size_t)M_DIM * K_DIM * 2;

    if (ws_size >= WB + XB) {
        unsigned short* Wbf = (unsigned short*)d_ws;
        unsigned short* Xbf = (unsigned short*)((char*)d_ws + WB);
        prep_kernel<<<dim3(30208), dim3(256), 0, stream>>>(qweight, qzeros, scales,
                                                           Wbf, x, Xbf);
        gemm256_kernel<<<dim3(688), dim3(512), 0, stream>>>(Xbf, Wbf, bias, out);
    } else {
        dim3 grid(N_DIM / 128, M_DIM / 128);
        gemm_fallback<<<grid, dim3(256), 0, stream>>>(x, qweight, qzeros, scales, bias, out);
    }
}